// Round 3
// baseline (285.087 us; speedup 1.0000x reference)
//
#include <hip/hip_runtime.h>

// SimpleRNN fused kernel for MI355X (gfx950).  B=32768, T=28, I=28, H=128, C=10.
//
// R10 = R7 structure with EXACTLY ONE structural change: no Xbuf.
//   R7-proven and kept verbatim:
//     - 4 waves/block, 16 batches/block; wave w owns h rows [32w, 32w+32)
//     - Sbuf[2][16*132] bf16 double-buffer (stride 132 measured conflict-free)
//     - scalar Pade(5,4) tanh (best measured, R4)
//     - __syncthreads() per step (vmcnt+lgkm drain; prefetch is issued a full
//       step ahead, so the vmcnt(0) drain is covered by the step's compute)
//     - bias-as-MFMA-C, 10 MFMA/wave/step
//   Changed vs R7:
//     - x streamed straight from global with a 1-step register prefetch
//       (R8 verified this addressing passes correctness and FETCH_SIZE stays
//       ~52 MB).  Deletes the 28.8 KB Xbuf + its staging VALU.
//     - LDS 37.2 KB -> 8.4 KB, so blocks/CU is no longer LDS-capped at 4:
//       __launch_bounds__(256,6) -> 6 blocks/CU = 24 waves/CU (R7 measured
//       35% occupancy; both R7/R8 show latency-bound counters, no pipe >60%,
//       so TLP is the lever).
//     - vectorized epilogue (uint2+f32x4, plain C).
//   Reverted vs failed R9 (absmax 1.33): no v_pk_*_f32 inline asm (suspect:
//   op_sel_hi defaults on packed-f32 VOP3P), no raw s_barrier.
//
// VGPR budget: persistent wfrag 32 + ufrag 8 + bias 8 = 48; + xa/xb 8 + acc 8
// + temps ~10-16 => ~70 (R7 measured 52 without the x regs).  Cap for 6
// waves/EU is ~80; if VGPR_Count pins at 85+ => spills => drop bound to 5.
//
// MFMA 16x16x32 bf16 layouts (m89/m91):
//   A[m=lane&15][k=(lane>>4)*8+j]  B[k=(lane>>4)*8+j][n=lane&15]
//   D[(lane>>4)*4+r][lane&15]

#define T_STEPS 28
#define S_STRIDE 132

typedef __attribute__((ext_vector_type(4))) float f32x4;
typedef __attribute__((ext_vector_type(8))) short short8;

#define MFMA16 __builtin_amdgcn_mfma_f32_16x16x32_bf16

__device__ __forceinline__ unsigned pack2(float lo, float hi) {
#if __has_builtin(__builtin_amdgcn_cvt_pk_bf16_f32)
  auto p = __builtin_amdgcn_cvt_pk_bf16_f32(lo, hi);   // RNE pack, 1 inst
  return __builtin_bit_cast(unsigned, p);
#else
  unsigned a = __builtin_bit_cast(unsigned, lo);
  a += 0x7FFFu + ((a >> 16) & 1u);
  unsigned b = __builtin_bit_cast(unsigned, hi);
  b += 0x7FFFu + ((b >> 16) & 1u);
  return (a >> 16) | (b & 0xFFFF0000u);
#endif
}

__device__ __forceinline__ short8 to_frag(f32x4 a, f32x4 b) {
  union { unsigned u[4]; short8 v; } r;
  r.u[0] = pack2(a[0], a[1]);
  r.u[1] = pack2(a[2], a[3]);
  r.u[2] = pack2(b[0], b[1]);
  r.u[3] = pack2(b[2], b[3]);
  return r.v;
}

__device__ __forceinline__ short8 load_frag64(const unsigned short* sp, int off) {
  // two b64 reads; measured conflict-free at the stride-132 pattern (R1/R3/R5)
  union { uint2 d[2]; short8 v; } r;
  r.d[0] = *(const uint2*)(sp + off);
  r.d[1] = *(const uint2*)(sp + off + 4);
  return r.v;
}

// Pade(5,4) tanh, scalar fp32 (best measured, R4): max err ~1.2e-3, den>=945.
__device__ __forceinline__ f32x4 tanh4(f32x4 z) {
  f32x4 x2 = z * z;
  f32x4 p = 945.0f + x2 * (105.0f + x2);
  f32x4 q = 945.0f + x2 * (420.0f + 15.0f * x2);
  f32x4 num = z * p;
  f32x4 r;
#pragma unroll
  for (int i = 0; i < 4; ++i) r[i] = __builtin_amdgcn_rcpf(q[i]);
  f32x4 t = num * r;
#pragma unroll
  for (int i = 0; i < 4; ++i) t[i] = __builtin_amdgcn_fmed3f(t[i], -1.0f, 1.0f);
  return t;
}

__global__ __launch_bounds__(256, 6) void rnn_fused(
    const float* __restrict__ x,  const float* __restrict__ Uw,
    const float* __restrict__ Ub, const float* __restrict__ Ww,
    const float* __restrict__ Wb, const float* __restrict__ Vw,
    const float* __restrict__ Vb, float* __restrict__ out) {
  __shared__ __align__(16) unsigned short Sbuf[2][16 * S_STRIDE];  // 8448 B

  const int tid  = threadIdx.x;
  const int w    = tid >> 6;
  const int lane = tid & 63;
  const int l15  = lane & 15;
  const int q    = lane >> 4;           // 0..3
  const int mrow = w * 32;              // h base for this wave (2 m-tiles)
  const int b0   = blockIdx.x * 16;

  const f32x4 zero4 = {0.f, 0.f, 0.f, 0.f};

  // ---- x streaming: per-lane base (batch l15, i-range q*8..q*8+7) ----
  const float* xp = x + (size_t)(b0 + l15) * 784 + q * 8;
  f32x4 xa = *(const f32x4*)xp;             // t=0: i = q*8..+3 (always valid)
  f32x4 xb = zero4;
  if (q < 3) xb = *(const f32x4*)(xp + 4);  // q=3 -> k>=28 stays zero

  // ---- persistent weight fragments ----
  short8 wfrag[2][4];   // [mt][kt]
  short8 ufrag[2];      // [mt], K=32 padded (k>=28 zeroed)
  f32x4  bias[2];       // Ub[h]+Wb[h] at D rows h = mrow + mt*16 + q*4 + r
#pragma unroll
  for (int mt = 0; mt < 2; ++mt) {
    const int h = mrow + mt * 16 + l15;
    const float* wp = Ww + h * 128 + q * 8;
#pragma unroll
    for (int kt = 0; kt < 4; ++kt) {
      wfrag[mt][kt] = to_frag(*(const f32x4*)wp, *(const f32x4*)(wp + 4));
      wp += 32;
    }
    const float* up = Uw + h * 28 + q * 8;
    f32x4 u0 = *(const f32x4*)up;
    f32x4 u1 = zero4;
    if (q < 3) u1 = *(const f32x4*)(up + 4);
    ufrag[mt] = to_frag(u0, u1);
    const int hb = mrow + mt * 16 + q * 4;
    bias[mt] = *(const f32x4*)(Wb + hb) + *(const f32x4*)(Ub + hb);
  }

  const int ro = l15 * S_STRIDE;                 // S row base (batch = l15)

  // ---- t = 0 (S=0: projection only), write Sbuf[1] ----
  {
    short8 xf = to_frag(xa, xb);
    const float* x1 = xp + 28;                   // prefetch t=1
    xa = *(const f32x4*)x1;
    if (q < 3) xb = *(const f32x4*)(x1 + 4);
    unsigned short* wp = &Sbuf[1][0];
#pragma unroll
    for (int mt = 0; mt < 2; ++mt) {
      f32x4 d0 = MFMA16(ufrag[mt], xf, bias[mt], 0, 0, 0);
      f32x4 t0 = tanh4(d0);
      uint2 dd; dd.x = pack2(t0[0], t0[1]); dd.y = pack2(t0[2], t0[3]);
      *(uint2*)(wp + ro + mrow + mt * 16 + q * 4) = dd;
    }
  }
  __syncthreads();

  // ---- t = 1 .. 27 ----
  const float* xn = xp + 56;                     // t=2 data onward
  f32x4 acc[2];
#pragma unroll 1
  for (int t = 1; t < T_STEPS; ++t) {
    short8 xf = to_frag(xa, xb);                 // step t's x fragment
    if (t < T_STEPS - 1) {                       // issue prefetch for t+1
      xa = *(const f32x4*)xn;
      if (q < 3) xb = *(const f32x4*)(xn + 4);
      xn += 28;
    }

    const unsigned short* sp = &Sbuf[t & 1][0] + ro + q * 8;

    // kt = 0 with bias as C-operand
    short8 sA = load_frag64(sp, 0);
#pragma unroll
    for (int mt = 0; mt < 2; ++mt)
      acc[mt] = MFMA16(wfrag[mt][0], sA, bias[mt], 0, 0, 0);
#pragma unroll
    for (int kt = 1; kt < 4; ++kt) {
      sA = load_frag64(sp, kt * 32);
#pragma unroll
      for (int mt = 0; mt < 2; ++mt)
        acc[mt] = MFMA16(wfrag[mt][kt], sA, acc[mt], 0, 0, 0);
    }
#pragma unroll
    for (int mt = 0; mt < 2; ++mt)
      acc[mt] = MFMA16(ufrag[mt], xf, acc[mt], 0, 0, 0);

    unsigned short* wp = &Sbuf[(t + 1) & 1][0];
#pragma unroll
    for (int mt = 0; mt < 2; ++mt) {
      f32x4 th = tanh4(acc[mt]);
      uint2 dd; dd.x = pack2(th[0], th[1]); dd.y = pack2(th[2], th[3]);
      *(uint2*)(wp + ro + mrow + mt * 16 + q * 4) = dd;
    }
    __syncthreads();
  }

  // ---- epilogue: out[b][c] = sum_h S[b][h]*Vw[c][h] + Vb[c] ----
  // Final S in Sbuf[0].  16 rows x 10 cols per block; vectorized reads.
  {
    const int r  = tid >> 4;        // 0..15
    const int c0 = tid & 15;        // only c0<10 active
    if (c0 < 10) {
      const float* vp = Vw + c0 * 128;
      const unsigned short* srow = &Sbuf[0][0] + r * S_STRIDE;
      float a0 = Vb[c0];
#pragma unroll
      for (int h = 0; h < 128; h += 4) {
        uint2 d  = *(const uint2*)(srow + h);       // 4 bf16, 8B aligned
        f32x4 v4 = *(const f32x4*)(vp + h);
        a0 += __builtin_bit_cast(float, d.x << 16) * v4[0];
        a0 += __builtin_bit_cast(float, d.x & 0xFFFF0000u) * v4[1];
        a0 += __builtin_bit_cast(float, d.y << 16) * v4[2];
        a0 += __builtin_bit_cast(float, d.y & 0xFFFF0000u) * v4[3];
      }
      out[(size_t)(b0 + r) * 10 + c0] = a0;
    }
  }
}

extern "C" void kernel_launch(void* const* d_in, const int* in_sizes, int n_in,
                              void* d_out, int out_size, void* d_ws, size_t ws_size,
                              hipStream_t stream) {
  const float* x  = (const float*)d_in[0];
  const float* Uw = (const float*)d_in[1];
  const float* Ub = (const float*)d_in[2];
  const float* Ww = (const float*)d_in[3];
  const float* Wb = (const float*)d_in[4];
  const float* Vw = (const float*)d_in[5];
  const float* Vb = (const float*)d_in[6];
  rnn_fused<<<2048, 256, 0, stream>>>(x, Uw, Ub, Ww, Wb, Vw, Vb, (float*)d_out);
}

// Round 4
// 216.022 us; speedup vs baseline: 1.3197x; 1.3197x over previous
//
#include <hip/hip_runtime.h>

// SimpleRNN fused kernel for MI355X (gfx950).  B=32768, T=28, I=28, H=128, C=10.
//
// R11 = R10 with ONE change: __launch_bounds__(256,6) -> (256,4).
//   R10's (256,6) forced the register allocator to 40 VGPRs, below the
//   48-reg persistent weight set -> inner-loop scratch spills: WRITE_SIZE
//   1.3 MB -> 163 MB, FETCH 50 -> 137 MB, dur 177 us (pure spill bandwidth:
//   308 MB @ 1.75 TB/s = 176 us).  (256,4) is measured-safe: R7 allocated
//   52 VGPRs, zero spills, with this same persistent set.
//
//   Kept from R10 (all verified working there):
//     - 4 waves/block, 16 batches/block; wave w owns h rows [32w, 32w+32)
//     - Sbuf[2][16*132] bf16 double-buffer (stride 132; R10 measured ZERO
//       bank conflicts with this exact layout)
//     - NO Xbuf: x streamed from global, 1-step register prefetch
//       (R10 FETCH shows no over-fetch from this; LDS 8.4 KB total ->
//       occupancy is VGPR-bound at ~floor(512/VGPR) blocks/CU, 5-8 vs
//       R7's LDS-capped 4)
//     - scalar Pade(5,4) tanh (best measured, R4)
//     - __syncthreads() per step; bias-as-MFMA-C; 10 MFMA/wave/step
//     - vectorized uint2/f32x4 epilogue
//
// MFMA 16x16x32 bf16 layouts (m89/m91):
//   A[m=lane&15][k=(lane>>4)*8+j]  B[k=(lane>>4)*8+j][n=lane&15]
//   D[(lane>>4)*4+r][lane&15]

#define T_STEPS 28
#define S_STRIDE 132

typedef __attribute__((ext_vector_type(4))) float f32x4;
typedef __attribute__((ext_vector_type(8))) short short8;

#define MFMA16 __builtin_amdgcn_mfma_f32_16x16x32_bf16

__device__ __forceinline__ unsigned pack2(float lo, float hi) {
#if __has_builtin(__builtin_amdgcn_cvt_pk_bf16_f32)
  auto p = __builtin_amdgcn_cvt_pk_bf16_f32(lo, hi);   // RNE pack, 1 inst
  return __builtin_bit_cast(unsigned, p);
#else
  unsigned a = __builtin_bit_cast(unsigned, lo);
  a += 0x7FFFu + ((a >> 16) & 1u);
  unsigned b = __builtin_bit_cast(unsigned, hi);
  b += 0x7FFFu + ((b >> 16) & 1u);
  return (a >> 16) | (b & 0xFFFF0000u);
#endif
}

__device__ __forceinline__ short8 to_frag(f32x4 a, f32x4 b) {
  union { unsigned u[4]; short8 v; } r;
  r.u[0] = pack2(a[0], a[1]);
  r.u[1] = pack2(a[2], a[3]);
  r.u[2] = pack2(b[0], b[1]);
  r.u[3] = pack2(b[2], b[3]);
  return r.v;
}

__device__ __forceinline__ short8 load_frag64(const unsigned short* sp, int off) {
  // two b64 reads; measured conflict-free at the stride-132 pattern (R1/R3/R5/R10)
  union { uint2 d[2]; short8 v; } r;
  r.d[0] = *(const uint2*)(sp + off);
  r.d[1] = *(const uint2*)(sp + off + 4);
  return r.v;
}

// Pade(5,4) tanh, scalar fp32 (best measured, R4): max err ~1.2e-3, den>=945.
__device__ __forceinline__ f32x4 tanh4(f32x4 z) {
  f32x4 x2 = z * z;
  f32x4 p = 945.0f + x2 * (105.0f + x2);
  f32x4 q = 945.0f + x2 * (420.0f + 15.0f * x2);
  f32x4 num = z * p;
  f32x4 r;
#pragma unroll
  for (int i = 0; i < 4; ++i) r[i] = __builtin_amdgcn_rcpf(q[i]);
  f32x4 t = num * r;
#pragma unroll
  for (int i = 0; i < 4; ++i) t[i] = __builtin_amdgcn_fmed3f(t[i], -1.0f, 1.0f);
  return t;
}

__global__ __launch_bounds__(256, 4) void rnn_fused(
    const float* __restrict__ x,  const float* __restrict__ Uw,
    const float* __restrict__ Ub, const float* __restrict__ Ww,
    const float* __restrict__ Wb, const float* __restrict__ Vw,
    const float* __restrict__ Vb, float* __restrict__ out) {
  __shared__ __align__(16) unsigned short Sbuf[2][16 * S_STRIDE];  // 8448 B

  const int tid  = threadIdx.x;
  const int w    = tid >> 6;
  const int lane = tid & 63;
  const int l15  = lane & 15;
  const int q    = lane >> 4;           // 0..3
  const int mrow = w * 32;              // h base for this wave (2 m-tiles)
  const int b0   = blockIdx.x * 16;

  const f32x4 zero4 = {0.f, 0.f, 0.f, 0.f};

  // ---- x streaming: per-lane base (batch l15, i-range q*8..q*8+7) ----
  const float* xp = x + (size_t)(b0 + l15) * 784 + q * 8;
  f32x4 xa = *(const f32x4*)xp;             // t=0: i = q*8..+3 (always valid)
  f32x4 xb = zero4;
  if (q < 3) xb = *(const f32x4*)(xp + 4);  // q=3 -> k>=28 stays zero

  // ---- persistent weight fragments ----
  short8 wfrag[2][4];   // [mt][kt]
  short8 ufrag[2];      // [mt], K=32 padded (k>=28 zeroed)
  f32x4  bias[2];       // Ub[h]+Wb[h] at D rows h = mrow + mt*16 + q*4 + r
#pragma unroll
  for (int mt = 0; mt < 2; ++mt) {
    const int h = mrow + mt * 16 + l15;
    const float* wp = Ww + h * 128 + q * 8;
#pragma unroll
    for (int kt = 0; kt < 4; ++kt) {
      wfrag[mt][kt] = to_frag(*(const f32x4*)wp, *(const f32x4*)(wp + 4));
      wp += 32;
    }
    const float* up = Uw + h * 28 + q * 8;
    f32x4 u0 = *(const f32x4*)up;
    f32x4 u1 = zero4;
    if (q < 3) u1 = *(const f32x4*)(up + 4);
    ufrag[mt] = to_frag(u0, u1);
    const int hb = mrow + mt * 16 + q * 4;
    bias[mt] = *(const f32x4*)(Wb + hb) + *(const f32x4*)(Ub + hb);
  }

  const int ro = l15 * S_STRIDE;                 // S row base (batch = l15)

  // ---- t = 0 (S=0: projection only), write Sbuf[1] ----
  {
    short8 xf = to_frag(xa, xb);
    const float* x1 = xp + 28;                   // prefetch t=1
    xa = *(const f32x4*)x1;
    if (q < 3) xb = *(const f32x4*)(x1 + 4);
    unsigned short* wp = &Sbuf[1][0];
#pragma unroll
    for (int mt = 0; mt < 2; ++mt) {
      f32x4 d0 = MFMA16(ufrag[mt], xf, bias[mt], 0, 0, 0);
      f32x4 t0 = tanh4(d0);
      uint2 dd; dd.x = pack2(t0[0], t0[1]); dd.y = pack2(t0[2], t0[3]);
      *(uint2*)(wp + ro + mrow + mt * 16 + q * 4) = dd;
    }
  }
  __syncthreads();

  // ---- t = 1 .. 27 ----
  const float* xn = xp + 56;                     // t=2 data onward
  f32x4 acc[2];
#pragma unroll 1
  for (int t = 1; t < T_STEPS; ++t) {
    short8 xf = to_frag(xa, xb);                 // step t's x fragment
    if (t < T_STEPS - 1) {                       // issue prefetch for t+1
      xa = *(const f32x4*)xn;
      if (q < 3) xb = *(const f32x4*)(xn + 4);
      xn += 28;
    }

    const unsigned short* sp = &Sbuf[t & 1][0] + ro + q * 8;

    // kt = 0 with bias as C-operand
    short8 sA = load_frag64(sp, 0);
#pragma unroll
    for (int mt = 0; mt < 2; ++mt)
      acc[mt] = MFMA16(wfrag[mt][0], sA, bias[mt], 0, 0, 0);
#pragma unroll
    for (int kt = 1; kt < 4; ++kt) {
      sA = load_frag64(sp, kt * 32);
#pragma unroll
      for (int mt = 0; mt < 2; ++mt)
        acc[mt] = MFMA16(wfrag[mt][kt], sA, acc[mt], 0, 0, 0);
    }
#pragma unroll
    for (int mt = 0; mt < 2; ++mt)
      acc[mt] = MFMA16(ufrag[mt], xf, acc[mt], 0, 0, 0);

    unsigned short* wp = &Sbuf[(t + 1) & 1][0];
#pragma unroll
    for (int mt = 0; mt < 2; ++mt) {
      f32x4 th = tanh4(acc[mt]);
      uint2 dd; dd.x = pack2(th[0], th[1]); dd.y = pack2(th[2], th[3]);
      *(uint2*)(wp + ro + mrow + mt * 16 + q * 4) = dd;
    }
    __syncthreads();
  }

  // ---- epilogue: out[b][c] = sum_h S[b][h]*Vw[c][h] + Vb[c] ----
  // Final S in Sbuf[0].  16 rows x 10 cols per block; vectorized reads.
  {
    const int r  = tid >> 4;        // 0..15
    const int c0 = tid & 15;        // only c0<10 active
    if (c0 < 10) {
      const float* vp = Vw + c0 * 128;
      const unsigned short* srow = &Sbuf[0][0] + r * S_STRIDE;
      float a0 = Vb[c0];
#pragma unroll
      for (int h = 0; h < 128; h += 4) {
        uint2 d  = *(const uint2*)(srow + h);       // 4 bf16, 8B aligned
        f32x4 v4 = *(const f32x4*)(vp + h);
        a0 += __builtin_bit_cast(float, d.x << 16) * v4[0];
        a0 += __builtin_bit_cast(float, d.x & 0xFFFF0000u) * v4[1];
        a0 += __builtin_bit_cast(float, d.y << 16) * v4[2];
        a0 += __builtin_bit_cast(float, d.y & 0xFFFF0000u) * v4[3];
      }
      out[(size_t)(b0 + r) * 10 + c0] = a0;
    }
  }
}

extern "C" void kernel_launch(void* const* d_in, const int* in_sizes, int n_in,
                              void* d_out, int out_size, void* d_ws, size_t ws_size,
                              hipStream_t stream) {
  const float* x  = (const float*)d_in[0];
  const float* Uw = (const float*)d_in[1];
  const float* Ub = (const float*)d_in[2];
  const float* Ww = (const float*)d_in[3];
  const float* Wb = (const float*)d_in[4];
  const float* Vw = (const float*)d_in[5];
  const float* Vb = (const float*)d_in[6];
  rnn_fused<<<2048, 256, 0, stream>>>(x, Uw, Ub, Ww, Wb, Vw, Vb, (float*)d_out);
}